// Round 10
// baseline (226.847 us; speedup 1.0000x reference)
//
#include <hip/hip_runtime.h>

// LSTM: B=2048, T=512, I=6, H=50, O=3. fp32 in/out, bf16 MFMA inner matmul.
//
// R13 = R11 (153.2us, proven best; R12's setprio+hoist reverted as measured
// -2.6us regression) + three serial-chain cuts:
//  - 4 independent MFMAs (C=0) + select-then-add: g = sel(a00,a10) +
//    sel(a01,a11). Breaks the mfma->mfma C-chain (depth 2xlat -> 1xlat +
//    cndmask/add, which overlap in the VALU while the matrix pipe drains).
//  - v_med3_f32 c-clamp (__builtin_amdgcn_fmed3f): 2 ops -> 1 on the
//    c->h dependency path.
//  - Xpack VALUE prefetch: next step's x-slice loaded into regs during the
//    cell phase; post-barrier bfr1 is a static-address Abuf read for ALL
//    lanes + 4 cndmask merge -> no divergent address select on the
//    post-barrier critical path. (quad2 lanes' Abuf read hits shorts
//    48..63 of the row: pad zeros + h48/49 -> finite, discarded by merge.)
// Wall model (closed): 718cy/step = 348 issue/SIMD (trans floor 112 +
// minimal ALU) + ~370 serial chain. 2 waves/SIMD is provably optimal
// (trans issue +56cy per extra wave). These cuts target the ~370.
// Carried from R11: NB=8, 512 thr, 8 waves, 1 WG/CU; R5 k'-map; broadcast-B
// (bb=col&7); 7-transcendental fused cell; weights pre-scaled L2E / 2*L2E;
// AP=88; XOR-swizzled Xpack; v_cvt_pk_bf16_f32 h-store; unconditional
// pad-safe h-write; unroll 8; 1 barrier/step, lgkm-only drain.

#define L2E 1.44269504088896340736f

typedef float    f32x4 __attribute__((ext_vector_type(4)));
typedef short    s16x8 __attribute__((ext_vector_type(8)));   // 8 bf16 bit-patterns
typedef unsigned u32x4 __attribute__((ext_vector_type(4)));

__device__ __forceinline__ float fast_exp2(float x){ return __builtin_amdgcn_exp2f(x); }
__device__ __forceinline__ float fast_rcp (float x){ return __builtin_amdgcn_rcpf(x); }

// float -> bf16 bits, round-to-nearest-even (weight staging only)
__device__ __forceinline__ unsigned short f2bf(float f){
  unsigned u = __builtin_bit_cast(unsigned, f);
  u = (u + 0x7FFFu + ((u >> 16) & 1u)) >> 16;
  return (unsigned short)u;
}

// single-instruction f32 -> bf16 (RNE) for the hot loop
__device__ __forceinline__ unsigned short f2bf_fast(float f){
  unsigned r;
  asm("v_cvt_pk_bf16_f32 %0, %1, %2" : "=v"(r) : "v"(f), "v"(0.0f));
  return (unsigned short)r;
}

// gates pre-scaled: g[0,1,3] = L2E*(i,f,o), g[2] = 2*L2E*g. Updates c,
// returns h. 7 transcendentals (5 exp2 + 2 rcp); med3 clamp on the chain.
__device__ __forceinline__ float lstm_cell(const f32x4 g, float& c){
  const float ef = fast_exp2(-g[1]);
  const float ei = fast_exp2(-g[0]);
  const float eg = fast_exp2(g[2]);          // |g2| <= ~33: no clamp needed
  const float A  = 1.0f + ef;
  const float Bq = 1.0f + ei;
  const float Cq = 1.0f + eg;
  const float BC = Bq * Cq;
  // c' = sig(f)*c + sig(i)*tanh(g) = (c*BC + (eg-1)*A) / (A*BC)
  const float num = fmaf(eg - 1.0f, A, c * BC);
  c = num * fast_rcp(A * BC);
  const float yc = __builtin_amdgcn_fmed3f(c * (2.0f * L2E), -115.f, 115.f);
  const float ec = fast_exp2(yc);
  const float eo = fast_exp2(-g[3]);
  const float r2 = fast_rcp((1.0f + eo) * (1.0f + ec));
  return (ec - 1.0f) * r2;                   // sig(o)*tanh(c)
}

constexpr int B_ = 2048, T_ = 512, I_ = 6, H_ = 50;
constexpr int NB = 8;       // batch rows per WG  (grid = 256 = 1 WG/CU)
constexpr int AP = 88;      // Abuf row pitch in bf16 elems (176 B: bank-spread)
constexpr int T6 = T_ * I_;

__global__ __launch_bounds__(512, 1)
void lstm_kernel(const float* __restrict__ x,
                 const float* __restrict__ W_ih, const float* __restrict__ W_hh,
                 const float* __restrict__ b_ih, const float* __restrict__ b_hh,
                 const float* __restrict__ W_out, const float* __restrict__ b_out,
                 float* __restrict__ out)
{
  // Xpack flat, XOR-swizzled: (t,b) slot = t*64 + (b*8 ^ ((t&7)<<3)) shorts.
  // Slot content = [x0..x5, bias=1.0, 0] = k' 48..55 of the B-operand.
  __shared__ unsigned short Xpack[T_ * NB * 8]; // 64 KB
  __shared__ unsigned short Abuf[2][NB * AP];   // 2.75 KB: h at 0..47,56,57
  __shared__ float Hlast[NB][H_];

  const int tid  = threadIdx.x;
  const int lane = tid & 63;
  const int wave = tid >> 6;     // 0..7
  const int col  = lane & 15;    // MFMA N index
  const int quad = lane >> 4;    // MFMA k-slice group
  const int bb   = col & 7;      // batch row (2-way broadcast)
  const bool lo  = col < 8;      // tile select: lo -> tile wave, hi -> wave+8
  const bool q2  = (quad == 2);  // lanes whose bfr1 slice is the x-feed
  const int b0   = blockIdx.x * NB;

  // ---- stage Xpack: thread tid handles t = tid (coalesced 24B reads) ----
  {
    const int tt = tid;          // 512 threads = 512 timesteps
    const int swz = (tt & 7) << 3;
    #pragma unroll
    for (int i = 0; i < NB; i++) {
      const float* xp = x + (size_t)(b0 + i) * T6 + tt * I_;
      const float2 a0 = *(const float2*)(xp);
      const float2 a1 = *(const float2*)(xp + 2);
      const float2 a2 = *(const float2*)(xp + 4);
      s16x8 w;
      w[0] = (short)f2bf(a0.x); w[1] = (short)f2bf(a0.y);
      w[2] = (short)f2bf(a1.x); w[3] = (short)f2bf(a1.y);
      w[4] = (short)f2bf(a2.x); w[5] = (short)f2bf(a2.y);
      w[6] = (short)0x3F80;     w[7] = 0;           // [bias=1.0, 0]
      *(s16x8*)&Xpack[tt * 64 + (i * 8 ^ swz)] = w;
    }
  }
  for (int i = tid; i < 2 * NB * AP; i += 512) (&Abuf[0][0])[i] = 0;

  // ---- weight fragments, pre-scaled, R5 k'-map. Wave w: tiles jt = w + 8*ti.
  // jt >= 13 -> jp >= 208 -> zero tiles (uniform 2-tile loop, balanced).
  // k': 0..47 -> W_hh[.][k'], 48..53 -> W_ih[.][k'-48], 54 -> bias,
  //     56,57 -> W_hh[.][48,49], else 0.
  s16x8 wfh[2][2];
  #pragma unroll
  for (int ti = 0; ti < 2; ti++) {
    const int jp = (wave + 8 * ti) * 16 + col;
    const bool ok = jp < 200;
    const int hidx = jp >> 2, gat = jp & 3;
    const int row = gat * 50 + hidx;
    const float scl = (gat == 2) ? (2.0f * L2E) : L2E;
    #pragma unroll
    for (int kh = 0; kh < 2; kh++) {
      s16x8 w;
      #pragma unroll
      for (int kk = 0; kk < 8; kk++) {
        const int k = kh * 32 + quad * 8 + kk;
        float v = 0.0f;
        if (ok) {
          if      (k < 48)  v = W_hh[row * 50 + k];
          else if (k < 54)  v = W_ih[row * 6 + (k - 48)];
          else if (k == 54) v = b_ih[row] + b_hh[row];
          else if (k == 56) v = W_hh[row * 50 + 48];
          else if (k == 57) v = W_hh[row * 50 + 49];
        }
        w[kk] = (short)f2bf(v * scl);
      }
      wfh[ti][kh] = w;
    }
  }

  // ---- lane pair identity: tile jt = wave + 8*(col>=8), hh = 4*jt + quad ----
  const int jt_r = wave + 8 * (lo ? 0 : 1);
  const int hh   = 4 * jt_r + quad;
  const bool valid = (jt_r < 13) && (hh < H_);
  const int pos   = hh + ((hh >= 48) ? 8 : 0);   // h48,h49 at 56,57; invalid
                                                 // lanes land in pad 58..71

  float c_ = 0.f, hreg = 0.f;
  const f32x4 zz = {0.f, 0.f, 0.f, 0.f};

  __syncthreads();

  // x-slice VALUE prefetch for t=0 (swz = 0 at t=0)
  u32x4 bxn = *(const u32x4*)&Xpack[bb * 8];

  #pragma unroll 8
  for (int t = 0; t < T_; t++) {
    const unsigned short* Ar = &Abuf[t & 1][0];
    unsigned short*       Aw = &Abuf[(t + 1) & 1][0];

    // B-frags, broadcast row (col&7). STATIC addresses for all lanes
    // (no divergent select on the post-barrier path); quad2's x-slice is
    // merged in from the prefetched register below.
    const unsigned short* arow = Ar + bb * AP;
    const s16x8 bfr0   = *(const s16x8*)(arow + quad * 8);      // k' 0..31
    const u32x4 b1raw  = *(const u32x4*)(arow + 32 + quad * 8); // k' 32..63
    const u32x4 b1m    = q2 ? bxn : b1raw;    // 4 cndmask, off the read path
    const s16x8 bfr1   = *(const s16x8*)&b1m;

    // 4 independent MFMAs (C=0): no mfma->mfma chain
    const f32x4 a00 = __builtin_amdgcn_mfma_f32_16x16x32_bf16(wfh[0][0], bfr0, zz, 0, 0, 0);
    const f32x4 a10 = __builtin_amdgcn_mfma_f32_16x16x32_bf16(wfh[1][0], bfr0, zz, 0, 0, 0);
    const f32x4 a01 = __builtin_amdgcn_mfma_f32_16x16x32_bf16(wfh[0][1], bfr1, zz, 0, 0, 0);
    const f32x4 a11 = __builtin_amdgcn_mfma_f32_16x16x32_bf16(wfh[1][1], bfr1, zz, 0, 0, 0);

    // prefetch x-slice for t+1 into regs (completes under the cell phase)
    {
      const int tn = (t + 1) & (T_ - 1);
      bxn = *(const u32x4*)&Xpack[tn * 64 + (bb * 8 ^ ((tn & 7) << 3))];
    }

    // tile select + combine: every lane holds its (bb, hh) quad
    f32x4 g;
    #pragma unroll
    for (int r = 0; r < 4; r++)
      g[r] = (lo ? a00[r] : a10[r]) + (lo ? a01[r] : a11[r]);

    hreg = lstm_cell(g, c_);
    Aw[bb * AP + pos] = f2bf_fast(hreg);   // unconditional: pad-safe

    __syncthreads();  // h visible to all waves; lgkm-only drain (no vmcnt)
  }

  // ---- epilogue: logits + softmax ----
  if (valid) Hlast[bb][hh] = hreg;
  __syncthreads();

  if (tid < NB) {
    float l[3];
    #pragma unroll
    for (int o = 0; o < 3; o++) {
      float s = b_out[o];
      for (int k = 0; k < H_; k++) s += W_out[o * H_ + k] * Hlast[tid][k];
      l[o] = s;
    }
    const float m  = fmaxf(l[0], fmaxf(l[1], l[2]));
    const float e0 = fast_exp2((l[0] - m) * L2E);
    const float e1 = fast_exp2((l[1] - m) * L2E);
    const float e2 = fast_exp2((l[2] - m) * L2E);
    const float inv = fast_rcp(e0 + e1 + e2);
    float* op = out + (size_t)(b0 + tid) * 3;
    op[0] = e0 * inv; op[1] = e1 * inv; op[2] = e2 * inv;
  }
}

extern "C" void kernel_launch(void* const* d_in, const int* in_sizes, int n_in,
                              void* d_out, int out_size, void* d_ws, size_t ws_size,
                              hipStream_t stream) {
  const float* x     = (const float*)d_in[0];
  const float* W_ih  = (const float*)d_in[1];
  const float* W_hh  = (const float*)d_in[2];
  const float* b_ih  = (const float*)d_in[3];
  const float* b_hh  = (const float*)d_in[4];
  const float* W_out = (const float*)d_in[5];
  const float* b_out = (const float*)d_in[6];
  lstm_kernel<<<B_ / NB, 512, 0, stream>>>(x, W_ih, W_hh, b_ih, b_hh,
                                           W_out, b_out, (float*)d_out);
}

// Round 11
// 207.768 us; speedup vs baseline: 1.0918x; 1.0918x over previous
//
#include <hip/hip_runtime.h>

// LSTM: B=2048, T=512, I=6, H=50, O=3. fp32 in/out, bf16 MFMA inner matmul.
//
// R14 = exact revert to R11 (153.2us, measured best) + med3 clamp (the one
// R13 component that is a pure issue reduction). R12 (setprio/hoist) and
// R13 (indep-MFMA select-add, value-prefetch merge) both measured negative:
// this kernel's wall is additive in issue; issue ADDITIONS fully hit the
// wall while issue cuts only half-reach it.
//
// Final measured ledger (cyc/step): R4 990 -> R5 860 -> R8 832 -> R9 750
// -> R10 737 -> R11 718. Wall model: ~348cy issue/SIMD (112 trans floor +
// minimal ALU/LDS issue) + ~370cy exposed chain (post-barrier ds_read
// ~120, MFMA dep, cell dep chain, write+drain+barrier). Verdicts: 2
// same-WG waves/SIMD optimal (R6/R7/R8); DS-count cut -> -2% (R10); VALU
// cut -> -2.6% (R11); setprio null (R12); chain surgery negative (R13);
// conflicts are one-time staging, off-path (R9/R10 byte-identical).
//
// Structure: NB=8, 512 thr, 8 waves, 1 WG/CU. R5 k'-map: k' 0..47 =
// W_hh cols 0..47, 48..53 = W_ih (x), 54 = bias, 56..57 = W_hh cols 48,49;
// quad2's bfr1 slice read straight from prepacked Xpack[t] (no per-step
// copy). Broadcast-B: bb = col&7 duplicates batch cols into 8..15 so every
// lane holds its (bb, hh) gate quad in the acc; tile select = 4 cndmask.
// Fused 7-transcendental cell (5 exp2 + 2 rcp), weights pre-scaled by
// L2E / 2*L2E. AP=88 bank-spread. 1 barrier/step, lgkm-only drain.

#define L2E 1.44269504088896340736f

typedef float  f32x4 __attribute__((ext_vector_type(4)));
typedef short  s16x8 __attribute__((ext_vector_type(8)));   // 8 bf16 bit-patterns

__device__ __forceinline__ float fast_exp2(float x){ return __builtin_amdgcn_exp2f(x); }
__device__ __forceinline__ float fast_rcp (float x){ return __builtin_amdgcn_rcpf(x); }

// float -> bf16 bits, round-to-nearest-even (weight staging only)
__device__ __forceinline__ unsigned short f2bf(float f){
  unsigned u = __builtin_bit_cast(unsigned, f);
  u = (u + 0x7FFFu + ((u >> 16) & 1u)) >> 16;
  return (unsigned short)u;
}

// single-instruction f32 -> bf16 (RNE) for the hot loop
__device__ __forceinline__ unsigned short f2bf_fast(float f){
  unsigned r;
  asm("v_cvt_pk_bf16_f32 %0, %1, %2" : "=v"(r) : "v"(f), "v"(0.0f));
  return (unsigned short)r;
}

// gates pre-scaled: g[0,1,3] = L2E*(i,f,o), g[2] = 2*L2E*g. Updates c,
// returns h. 7 transcendentals (5 exp2 + 2 rcp); med3 clamp on the chain.
__device__ __forceinline__ float lstm_cell(const f32x4 g, float& c){
  const float ef = fast_exp2(-g[1]);
  const float ei = fast_exp2(-g[0]);
  const float eg = fast_exp2(g[2]);          // |g2| <= ~33: no clamp needed
  const float A  = 1.0f + ef;
  const float Bq = 1.0f + ei;
  const float Cq = 1.0f + eg;
  const float BC = Bq * Cq;
  // c' = sig(f)*c + sig(i)*tanh(g) = (c*BC + (eg-1)*A) / (A*BC)
  const float num = fmaf(eg - 1.0f, A, c * BC);
  c = num * fast_rcp(A * BC);
  const float yc = __builtin_amdgcn_fmed3f(c * (2.0f * L2E), -115.f, 115.f);
  const float ec = fast_exp2(yc);
  const float eo = fast_exp2(-g[3]);
  const float r2 = fast_rcp((1.0f + eo) * (1.0f + ec));
  return (ec - 1.0f) * r2;                   // sig(o)*tanh(c)
}

constexpr int B_ = 2048, T_ = 512, I_ = 6, H_ = 50;
constexpr int NB = 8;       // batch rows per WG  (grid = 256 = 1 WG/CU)
constexpr int AP = 88;      // Abuf row pitch in bf16 elems (176 B: bank-spread)
constexpr int T6 = T_ * I_;

__global__ __launch_bounds__(512, 1)
void lstm_kernel(const float* __restrict__ x,
                 const float* __restrict__ W_ih, const float* __restrict__ W_hh,
                 const float* __restrict__ b_ih, const float* __restrict__ b_hh,
                 const float* __restrict__ W_out, const float* __restrict__ b_out,
                 float* __restrict__ out)
{
  // Xpack flat, XOR-swizzled: (t,b) slot = t*64 + (b*8 ^ ((t&7)<<3)) shorts.
  // Slot content = [x0..x5, bias=1.0, 0] = k' 48..55 of the B-operand.
  __shared__ unsigned short Xpack[T_ * NB * 8]; // 64 KB
  __shared__ unsigned short Abuf[2][NB * AP];   // 2.75 KB: h at 0..47,56,57
  __shared__ float Hlast[NB][H_];

  const int tid  = threadIdx.x;
  const int lane = tid & 63;
  const int wave = tid >> 6;     // 0..7
  const int col  = lane & 15;    // MFMA N index
  const int quad = lane >> 4;    // MFMA k-slice group
  const int bb   = col & 7;      // batch row (2-way broadcast)
  const bool lo  = col < 8;      // tile select: lo -> tile wave, hi -> wave+8
  const int b0   = blockIdx.x * NB;

  // ---- stage Xpack: thread tid handles t = tid (coalesced 24B reads) ----
  {
    const int tt = tid;          // 512 threads = 512 timesteps
    const int swz = (tt & 7) << 3;
    #pragma unroll
    for (int i = 0; i < NB; i++) {
      const float* xp = x + (size_t)(b0 + i) * T6 + tt * I_;
      const float2 a0 = *(const float2*)(xp);
      const float2 a1 = *(const float2*)(xp + 2);
      const float2 a2 = *(const float2*)(xp + 4);
      s16x8 w;
      w[0] = (short)f2bf(a0.x); w[1] = (short)f2bf(a0.y);
      w[2] = (short)f2bf(a1.x); w[3] = (short)f2bf(a1.y);
      w[4] = (short)f2bf(a2.x); w[5] = (short)f2bf(a2.y);
      w[6] = (short)0x3F80;     w[7] = 0;           // [bias=1.0, 0]
      *(s16x8*)&Xpack[tt * 64 + (i * 8 ^ swz)] = w;
    }
  }
  for (int i = tid; i < 2 * NB * AP; i += 512) (&Abuf[0][0])[i] = 0;

  // ---- weight fragments, pre-scaled, R5 k'-map. Wave w: tiles jt = w + 8*ti.
  // jt >= 13 -> jp >= 208 -> zero tiles (uniform 2-tile loop, balanced).
  // k': 0..47 -> W_hh[.][k'], 48..53 -> W_ih[.][k'-48], 54 -> bias,
  //     56,57 -> W_hh[.][48,49], else 0.
  s16x8 wfh[2][2];
  #pragma unroll
  for (int ti = 0; ti < 2; ti++) {
    const int jp = (wave + 8 * ti) * 16 + col;
    const bool ok = jp < 200;
    const int hidx = jp >> 2, gat = jp & 3;
    const int row = gat * 50 + hidx;
    const float scl = (gat == 2) ? (2.0f * L2E) : L2E;
    #pragma unroll
    for (int kh = 0; kh < 2; kh++) {
      s16x8 w;
      #pragma unroll
      for (int kk = 0; kk < 8; kk++) {
        const int k = kh * 32 + quad * 8 + kk;
        float v = 0.0f;
        if (ok) {
          if      (k < 48)  v = W_hh[row * 50 + k];
          else if (k < 54)  v = W_ih[row * 6 + (k - 48)];
          else if (k == 54) v = b_ih[row] + b_hh[row];
          else if (k == 56) v = W_hh[row * 50 + 48];
          else if (k == 57) v = W_hh[row * 50 + 49];
        }
        w[kk] = (short)f2bf(v * scl);
      }
      wfh[ti][kh] = w;
    }
  }

  // ---- lane pair identity: tile jt = wave + 8*(col>=8), hh = 4*jt + quad ----
  const int jt_r = wave + 8 * (lo ? 0 : 1);
  const int hh   = 4 * jt_r + quad;
  const bool valid = (jt_r < 13) && (hh < H_);
  const int pos   = hh + ((hh >= 48) ? 8 : 0);   // h48,h49 at 56,57; invalid
                                                 // lanes land in pad 58..71

  float c_ = 0.f, hreg = 0.f;
  const f32x4 zz = {0.f, 0.f, 0.f, 0.f};

  __syncthreads();

  #pragma unroll 8
  for (int t = 0; t < T_; t++) {
    const unsigned short* Ar = &Abuf[t & 1][0];
    unsigned short*       Aw = &Abuf[(t + 1) & 1][0];

    // B-frags, broadcast row (col&7). quad2's bfr1 slice (k' 48..55) is
    // [x|bias|0], read straight from Xpack via per-lane address select.
    const unsigned short* arow = Ar + bb * AP;
    const s16x8 bfr0 = *(const s16x8*)(arow + quad * 8);        // k' 0..31
    const unsigned short* p1 = (quad == 2)
        ? &Xpack[t * 64 + (bb * 8 ^ ((t & 7) << 3))]
        : (arow + 32 + quad * 8);
    const s16x8 bfr1 = *(const s16x8*)p1;                       // k' 32..63

    // 2 MFMAs per tile (K=64 covers h + x + bias)
    f32x4 a[2];
    #pragma unroll
    for (int ti = 0; ti < 2; ti++) {
      a[ti] = __builtin_amdgcn_mfma_f32_16x16x32_bf16(wfh[ti][0], bfr0, zz,    0, 0, 0);
      a[ti] = __builtin_amdgcn_mfma_f32_16x16x32_bf16(wfh[ti][1], bfr1, a[ti], 0, 0, 0);
    }

    // tile select: every lane already holds its (bb, hh) quad
    f32x4 g;
    #pragma unroll
    for (int r = 0; r < 4; r++) g[r] = lo ? a[0][r] : a[1][r];

    hreg = lstm_cell(g, c_);
    Aw[bb * AP + pos] = f2bf_fast(hreg);   // unconditional: pad-safe

    __syncthreads();  // h visible to all waves; lgkm-only drain (no vmcnt)
  }

  // ---- epilogue: logits + softmax ----
  if (valid) Hlast[bb][hh] = hreg;
  __syncthreads();

  if (tid < NB) {
    float l[3];
    #pragma unroll
    for (int o = 0; o < 3; o++) {
      float s = b_out[o];
      for (int k = 0; k < H_; k++) s += W_out[o * H_ + k] * Hlast[tid][k];
      l[o] = s;
    }
    const float m  = fmaxf(l[0], fmaxf(l[1], l[2]));
    const float e0 = fast_exp2((l[0] - m) * L2E);
    const float e1 = fast_exp2((l[1] - m) * L2E);
    const float e2 = fast_exp2((l[2] - m) * L2E);
    const float inv = fast_rcp(e0 + e1 + e2);
    float* op = out + (size_t)(b0 + tid) * 3;
    op[0] = e0 * inv; op[1] = e1 * inv; op[2] = e2 * inv;
  }
}

extern "C" void kernel_launch(void* const* d_in, const int* in_sizes, int n_in,
                              void* d_out, int out_size, void* d_ws, size_t ws_size,
                              hipStream_t stream) {
  const float* x     = (const float*)d_in[0];
  const float* W_ih  = (const float*)d_in[1];
  const float* W_hh  = (const float*)d_in[2];
  const float* b_ih  = (const float*)d_in[3];
  const float* b_hh  = (const float*)d_in[4];
  const float* W_out = (const float*)d_in[5];
  const float* b_out = (const float*)d_in[6];
  lstm_kernel<<<B_ / NB, 512, 0, stream>>>(x, W_ih, W_hh, b_ih, b_hh,
                                           W_out, b_out, (float*)d_out);
}